// Round 2
// baseline (1044.958 us; speedup 1.0000x reference)
//
#include <hip/hip_runtime.h>

// CTC total-score forward (log-semiring), B=32 T=800 C=5000 L=100, S=201.
//
// Single pipelined kernel, 256 blocks:
//   blocks 0..31   (alpha): 1 consumer wave (serial alpha recursion, states in
//                  registers) + 4 producer waves copying dense compressed rows
//                  ws[b][t][RP] into double-buffered LDS. Producers acquire-spin
//                  on a per-(b,chunk) flag before copying.
//   blocks 32..255 (gather): COALESCED full-row staging: stream each 20KB
//                  log-prob row into LDS with float4 loads (double-buffered),
//                  then 104 lanes select the target classes and write the
//                  compressed row to ws. Release-store the chunk flag.
// Task order is chunk-major so early chunks land first and the serial alpha
// march overlaps the gather. All 256 blocks are co-resident (54.7KB LDS ->
// 2 blocks/CU capacity), so flag-spinning cannot deadlock.

constexpr int B  = 32;
constexpr int T  = 800;
constexpr int C  = 5000;
constexpr int L  = 100;
constexpr int S  = 2 * L + 1;    // 201
constexpr float NEGV = -1e30f;

constexpr int RP  = 104;         // compressed row: [0..99]=targets,[100]=blank,[101..103]=pad
constexpr int CH  = 64;          // timesteps per chunk
constexpr int CHE = CH * RP;     // 6656 floats per chunk
constexpr int NCHUNK = (T + CH - 1) / CH;   // 13
constexpr int T_PAD  = NCHUNK * CH;         // 832 (chunk-aligned row count in ws)
constexpr int NT  = NCHUNK * B;             // 416 gather tasks
constexpr int BLK = 320;         // 5 waves
constexpr int NALPHA  = B;       // 32 alpha blocks
constexpr int NGATHER = 224;     // gather blocks
constexpr int NBLOCKS = NALPHA + NGATHER;   // 256
constexpr int ROWV4   = C / 4;   // 1250 float4 per row

constexpr size_t DATA_FLOATS = (size_t)B * T_PAD * RP;      // 2,768,896
constexpr size_t WS_NEED = (DATA_FLOATS + NT) * sizeof(float);

// LDS arena: alpha needs 2*CHE*4 + L*4 + 256*4 = 54,672 B; gather needs 40,400 B.
constexpr int ARENA_BYTES = 2 * CHE * 4 + L * 4 + 256 * 4;  // 54,672

__device__ __forceinline__ float lse2(float a, float b) {
    const float m = fmaxf(a, b);
    return m + __logf(__expf(a - m) + __expf(b - m));
}
__device__ __forceinline__ float lse3(float a, float b, float c) {
    const float m = fmaxf(a, fmaxf(b, c));
    return m + __logf(__expf(a - m) + __expf(b - m) + __expf(c - m));
}

__global__ __launch_bounds__(BLK) void ctc_pipe(
    const float* __restrict__ lp, const int* __restrict__ targets,
    const int* __restrict__ il_, const int* __restrict__ tl_,
    float* __restrict__ out, float* __restrict__ ws, int* __restrict__ flags)
{
    alignas(16) __shared__ char arena[ARENA_BYTES];
    const int bid = blockIdx.x;
    const int tid = threadIdx.x;

    if (bid >= NALPHA) {
        // ================= gather role =================
        float* rowbuf = (float*)arena;                    // [2][5000]
        int*   tgt    = (int*)(arena + 2 * C * 4);        // [L]
        const int gb = bid - NALPHA;

        for (int task = gb; task < NT; task += NGATHER) {
            const int b     = task & 31;
            const int chunk = task >> 5;
            const int t0    = chunk * CH;
            const int il    = il_[b];
            int rows = il - t0; rows = rows > CH ? CH : rows;

            if (rows > 0) {
                if (tid < L) tgt[tid] = targets[b * L + tid];
                const float* __restrict__ src = lp + (size_t)(b * T + t0) * C;
                float* __restrict__ dstb = ws + ((size_t)b * T_PAD + t0) * RP;
                // prologue: row 0 -> rowbuf[0]
                {
                    const float4* s4 = (const float4*)src;
                    float4* d4 = (float4*)rowbuf;
                    for (int j = tid; j < ROWV4; j += BLK) d4[j] = s4[j];
                }
                __syncthreads();
                for (int r = 0; r < rows; ++r) {
                    if (r + 1 < rows) {          // prefetch row r+1
                        const float4* s4 = (const float4*)(src + (size_t)(r + 1) * C);
                        float4* d4 = (float4*)(rowbuf + ((r + 1) & 1) * C);
                        for (int j = tid; j < ROWV4; j += BLK) d4[j] = s4[j];
                    }
                    const float* rb = rowbuf + (r & 1) * C;
                    if (tid < RP) {
                        float v;
                        if      (tid < 100)  v = rb[tgt[tid]];
                        else if (tid == 100) v = rb[0];       // blank
                        else                 v = NEGV;        // pad
                        dstb[(size_t)r * RP + tid] = v;
                    }
                    __syncthreads();
                }
            }
            __threadfence();
            if (tid == 0)
                __hip_atomic_store(flags + task, 1, __ATOMIC_RELEASE,
                                   __HIP_MEMORY_SCOPE_AGENT);
            __syncthreads();   // protect tgt/rowbuf reuse across tasks
        }
        return;
    }

    // ================= alpha role =================
    float* buf0 = (float*)arena;                          // [CHE]
    float* buf1 = (float*)(arena + CHE * 4);              // [CHE]
    int*   tgt  = (int*)(arena + 2 * CHE * 4);            // [L]
    float* sm   = (float*)(arena + 2 * CHE * 4 + L * 4);  // [256]

    const int b  = bid;
    const int il = il_[b];
    const int nch = (il + CH - 1) / CH;
    const float* __restrict__ base = ws + (size_t)b * T_PAD * RP;

    if (tid < L) tgt[tid] = targets[b * L + tid];
    __syncthreads();

    const int lane = tid;
    const int s0   = 4 * lane;
    bool skip1 = false, skip3 = false;
    bool v0 = false, v1 = false, v2c = false, v3 = false;
    int  offt = 0;
    if (tid < 64) {
        const int l2 = 2 * lane;
        const int i1 = (l2     < L) ? l2     : L - 1;
        const int i3 = (l2 + 1 < L) ? l2 + 1 : L - 1;
        const int ip = (l2 - 1 >= 0) ? l2 - 1 : 0;
        const int c1i = tgt[i1], c3i = tgt[i3], cpi = tgt[ip];
        skip1 = (lane == 0) ? true : (c1i != cpi);
        skip3 = (c3i != c1i);
        v0  = (s0     < S);
        v1  = (s0 + 1 < S);
        v2c = (s0 + 2 < S);
        v3  = (s0 + 3 < S);
        offt = (l2 <= 100) ? l2 : 100;   // even -> 8B aligned float2
    }

    float a0 = NEGV, a1v = NEGV, a2v = NEGV, a3v = NEGV;

    for (int c = -1; c < nch; ++c) {
        if (tid >= 64) {
            // producers: wait for chunk c+1, then dense coalesced copy
            const int c2 = c + 1;
            if (c2 < nch) {
                const int task = (c2 << 5) + b;
                while (__hip_atomic_load(flags + task, __ATOMIC_ACQUIRE,
                                         __HIP_MEMORY_SCOPE_AGENT) == 0) {
                    __builtin_amdgcn_s_sleep(2);
                }
                const int rows = ((il - c2 * CH) < CH) ? (il - c2 * CH) : CH;
                const int jmax = rows * (RP / 4);
                float4* __restrict__ dst = (float4*)((c2 & 1) ? buf1 : buf0);
                const float4* __restrict__ src =
                    (const float4*)(base + (size_t)c2 * CHE);
                for (int j = tid - 64; j < jmax; j += 256) dst[j] = src[j];
            }
        } else if (c >= 0) {
            // consumer: process chunk c
            const float* bp = (c & 1) ? buf1 : buf0;
            const int tbase = c * CH;
            const int rmax  = (il - tbase < CH) ? (il - tbase) : CH;
            float2 tv = *(const float2*)(bp + offt);
            float  bl = bp[100];
            for (int r = 0; r < rmax; ++r) {
                const float2 ctv = tv;
                const float  cbl = bl;
                if (r + 1 < rmax) {
                    tv = *(const float2*)(bp + (r + 1) * RP + offt);
                    bl = bp[(r + 1) * RP + 100];
                }
                const int t = tbase + r;
                if (t == 0) {
                    a0  = (lane == 0) ? cbl   : NEGV;
                    a1v = (lane == 0) ? ctv.x : NEGV;
                    a2v = NEGV; a3v = NEGV;
                } else {
                    float up3 = __shfl_up(a3v, 1);   // state 4l-1
                    if (lane == 0) up3 = NEGV;
                    const float n0 = lse2(a0, up3) + cbl;
                    const float n1 = (skip1 ? lse3(a1v, a0, up3) : lse2(a1v, a0)) + ctv.x;
                    const float n2 = lse2(a2v, a1v) + cbl;
                    const float n3 = (skip3 ? lse3(a3v, a2v, a1v) : lse2(a3v, a2v)) + ctv.y;
                    a0  = v0  ? n0 : NEGV;
                    a1v = v1  ? n1 : NEGV;
                    a2v = v2c ? n2 : NEGV;
                    a3v = v3  ? n3 : NEGV;
                }
            }
        }
        __syncthreads();
    }

    if (tid < 64) {
        sm[s0 + 0] = a0;
        sm[s0 + 1] = a1v;
        sm[s0 + 2] = a2v;
        sm[s0 + 3] = a3v;
    }
    __syncthreads();

    if (tid == 0) {
        const int tl = tl_[b];
        const float tot = lse2(sm[2 * tl], sm[2 * tl - 1]);
        const bool finite = tot > (NEGV * 0.5f);
        atomicAdd(out + 0, finite ? tot : 0.0f);
        atomicAdd(out + 1, finite ? (float)il : 0.0f);
        atomicAdd(out + 2, (float)il);
    }
}

// ---------------------------------------------------------------------------
// Fallback: original fused kernel (used only if ws_size < WS_NEED).
// ---------------------------------------------------------------------------
constexpr int SPF  = 204;
constexpr int CHF  = 32;
constexpr int CHEF = CHF * SPF;
constexpr int NPROD = 256;

__global__ __launch_bounds__(BLK) void ctc_fused(
    const float* __restrict__ lp, const int* __restrict__ targets,
    const int* __restrict__ il_, const int* __restrict__ tl_,
    float* __restrict__ out)
{
    __shared__ float buf[2][CHEF];
    __shared__ int   tgt[L];
    __shared__ float sm[256];

    const int b   = blockIdx.x;
    const int tid = threadIdx.x;
    const int il  = il_[b];
    const int nch = (il + CHF - 1) / CHF;
    const float* __restrict__ base = lp + (size_t)b * T * C;

    if (tid < L) tgt[tid] = targets[b * L + tid];
    __syncthreads();

    const int lane = tid;
    const int s0   = 4 * lane;
    bool skip1 = false, skip3 = false;
    bool v0 = false, v1 = false, v2c = false, v3 = false;
    int  off = 0;
    if (tid < 64) {
        const int l2 = 2 * lane;
        const int i1 = (l2     < L) ? l2     : L - 1;
        const int i3 = (l2 + 1 < L) ? l2 + 1 : L - 1;
        const int ip = (l2 - 1 >= 0) ? l2 - 1 : 0;
        const int c1i = tgt[i1], c3i = tgt[i3], cpi = tgt[ip];
        skip1 = (lane == 0) ? true : (c1i != cpi);
        skip3 = (c3i != c1i);
        v0  = (s0     < S);
        v1  = (s0 + 1 < S);
        v2c = (s0 + 2 < S);
        v3  = (s0 + 3 < S);
        off = (s0 <= 200) ? s0 : 200;
    }

    float a0 = NEGV, a1v = NEGV, a2v = NEGV, a3v = NEGV;

    for (int c = -1; c < nch; ++c) {
        if (tid >= 64) {
            const int c2 = c + 1;
            if (c2 < nch) {
                float* dst = buf[c2 & 1];
                const int tbase = c2 * CHF;
                const int pid = tid - 64;
#pragma unroll
                for (int bat = 0; bat < 2; ++bat) {
                    float v[13];
                    int   fl[13];
#pragma unroll
                    for (int j = 0; j < 13; ++j) {
                        const int flat = (bat * 13 + j) * NPROD + pid;
                        fl[j] = flat;
                        float val = NEGV;
                        if (flat < CHEF) {
                            const int r = flat / SPF;
                            const int s = flat - r * SPF;
                            const int t = tbase + r;
                            if (t < il) {
                                const int cls = ((s & 1) && s < S) ? tgt[s >> 1] : 0;
                                val = base[(size_t)t * C + cls];
                            }
                        }
                        v[j] = val;
                    }
#pragma unroll
                    for (int j = 0; j < 13; ++j)
                        if (fl[j] < CHEF) dst[fl[j]] = v[j];
                }
            }
        } else if (c >= 0) {
            const float* bp = buf[c & 1];
            const int tbase = c * CHF;
            const int rmax  = (il - tbase < CHF) ? (il - tbase) : CHF;
            float4 e = *(const float4*)(bp + off);
            for (int r = 0; r < rmax; ++r) {
                const float4 cur = e;
                if (r + 1 < rmax) e = *(const float4*)(bp + (r + 1) * SPF + off);
                const int t = tbase + r;
                if (t == 0) {
                    a0  = (lane == 0) ? cur.x : NEGV;
                    a1v = (lane == 0) ? cur.y : NEGV;
                    a2v = NEGV; a3v = NEGV;
                } else {
                    float up3 = __shfl_up(a3v, 1);
                    if (lane == 0) up3 = NEGV;
                    const float n0 = lse2(a0, up3) + cur.x;
                    const float n1 = (skip1 ? lse3(a1v, a0, up3) : lse2(a1v, a0)) + cur.y;
                    const float n2 = lse2(a2v, a1v) + cur.z;
                    const float n3 = (skip3 ? lse3(a3v, a2v, a1v) : lse2(a3v, a2v)) + cur.w;
                    a0  = v0  ? n0 : NEGV;
                    a1v = v1  ? n1 : NEGV;
                    a2v = v2c ? n2 : NEGV;
                    a3v = v3  ? n3 : NEGV;
                }
            }
        }
        __syncthreads();
    }

    if (tid < 64) {
        sm[s0 + 0] = a0;
        sm[s0 + 1] = a1v;
        sm[s0 + 2] = a2v;
        sm[s0 + 3] = a3v;
    }
    __syncthreads();

    if (tid == 0) {
        const int tl = tl_[b];
        const float tot = lse2(sm[2 * tl], sm[2 * tl - 1]);
        const bool finite = tot > (NEGV * 0.5f);
        atomicAdd(out + 0, finite ? tot : 0.0f);
        atomicAdd(out + 1, finite ? (float)il : 0.0f);
        atomicAdd(out + 2, (float)il);
    }
}

extern "C" void kernel_launch(void* const* d_in, const int* in_sizes, int n_in,
                              void* d_out, int out_size, void* d_ws, size_t ws_size,
                              hipStream_t stream)
{
    const float* lp      = (const float*)d_in[0];   // (B,T,C) f32
    const int*   targets = (const int*)d_in[1];     // (B,L)
    const int*   il      = (const int*)d_in[2];     // (B,)
    const int*   tl      = (const int*)d_in[3];     // (B,)
    float* out = (float*)d_out;                     // 3 floats

    hipMemsetAsync(d_out, 0, (size_t)out_size * sizeof(float), stream);

    if (ws_size >= WS_NEED) {
        float* ws   = (float*)d_ws;
        int*  flags = (int*)(ws + DATA_FLOATS);
        hipMemsetAsync(flags, 0, NT * sizeof(int), stream);
        ctc_pipe<<<NBLOCKS, BLK, 0, stream>>>(lp, targets, il, tl, out, ws, flags);
    } else {
        ctc_fused<<<B, BLK, 0, stream>>>(lp, targets, il, tl, out);
    }
}

// Round 3
// 934.377 us; speedup vs baseline: 1.1183x; 1.1183x over previous
//
#include <hip/hip_runtime.h>

// CTC total-score forward (log-semiring), B=32 T=800 C=5000 L=100, S=201.
//
// Single pipelined kernel, 256 blocks (all co-resident, 2 blocks/CU capacity):
//   blocks 0..31   (alpha): 1 consumer wave (serial alpha recursion, states in
//                  registers) + 4 producer waves copying dense compressed rows
//                  ws[b][t][RP] into double-buffered LDS. Producers acquire-spin
//                  on a per-(b,chunk) completion COUNTER.
//   blocks 32..255 (gather): 4 independent waves, NO barriers. Each wave owns a
//                  private 20KB LDS row buffer, stages a full 20KB log-prob row
//                  with 20x global_load_lds (16B, wave-uniform base + lane*16),
//                  one vmcnt(0), then 104-class select -> ws. One HBM latency
//                  per row, 20KB in flight per wave, 896 waves => BW-bound.
// Task order is chunk-major so early chunks land first and the serial alpha
// march overlaps the gather.

constexpr int B  = 32;
constexpr int T  = 800;
constexpr int C  = 5000;
constexpr int L  = 100;
constexpr int S  = 2 * L + 1;    // 201
constexpr float NEGV = -1e30f;

constexpr int RP  = 104;         // compressed row: [0..99]=targets,[100]=blank,[101..103]=pad
constexpr int CH  = 64;          // timesteps per chunk
constexpr int CHE = CH * RP;     // 6656 floats per chunk
constexpr int NCHUNK = (T + CH - 1) / CH;   // 13
constexpr int T_PAD  = NCHUNK * CH;         // 832
constexpr int NT  = NCHUNK * B;             // 416 gather tasks
constexpr int BLK = 320;         // 5 waves
constexpr int NALPHA  = B;       // 32 alpha blocks
constexpr int NGATHER = 224;     // gather blocks
constexpr int NBLOCKS = NALPHA + NGATHER;   // 256
constexpr int ROWV4   = C / 4;   // 1250 float4 per row
constexpr int NGW     = 4;       // gather waves per block (wave 4 idles)
constexpr int WB4     = 1280;    // float4 slots per wave buffer (20*64)

constexpr size_t DATA_FLOATS = (size_t)B * T_PAD * RP;      // 2,768,896
constexpr size_t WS_NEED = (DATA_FLOATS + NT) * sizeof(float);

// LDS arena: gather 4*WB4*16 = 81,920 B; alpha needs 54,672 B. 2 blocks/CU.
constexpr int ARENA_BYTES = NGW * WB4 * 16;   // 81,920

__device__ __forceinline__ float lse2(float a, float b) {
    const float m = fmaxf(a, b);
    return m + __logf(__expf(a - m) + __expf(b - m));
}
__device__ __forceinline__ float lse3(float a, float b, float c) {
    const float m = fmaxf(a, fmaxf(b, c));
    return m + __logf(__expf(a - m) + __expf(b - m) + __expf(c - m));
}

__global__ __launch_bounds__(BLK) void ctc_pipe(
    const float* __restrict__ lp, const int* __restrict__ targets,
    const int* __restrict__ il_, const int* __restrict__ tl_,
    float* __restrict__ out, float* __restrict__ ws, int* __restrict__ ctr)
{
    alignas(16) __shared__ char arena[ARENA_BYTES];
    const int bid = blockIdx.x;
    const int tid = threadIdx.x;

    if (bid >= NALPHA) {
        // ================= gather role: 4 free-running waves =================
        const int wv   = tid >> 6;
        const int lane = tid & 63;
        if (wv >= NGW) return;                       // wave 4 idles
        float4* mybuf4 = ((float4*)arena) + wv * WB4;
        float*  mybuf  = (float*)mybuf4;
        const int gb = bid - NALPHA;

        for (int task = gb; task < NT; task += NGATHER) {
            const int b     = task & 31;
            const int chunk = task >> 5;
            const int t0    = chunk * CH;
            const int il    = il_[b];
            int rows = il - t0; rows = rows > CH ? CH : rows;
            if (rows <= 0) continue;

            // per-task class indices for this lane's two slots
            const int cls0 = targets[b * L + lane];          // slot = lane (<100)
            int cls1 = -1;                                   // slot = lane+64
            if      (lane + 64 <  100) cls1 = targets[b * L + lane + 64];
            else if (lane + 64 == 100) cls1 = 0;             // blank

            const float* __restrict__ src  = lp + (size_t)(b * T + t0) * C;
            float*       __restrict__ dstb = ws + ((size_t)b * T_PAD + t0) * RP;

            int done = 0;
            for (int r = wv; r < rows; r += NGW) {
                const float4* s4 = (const float4*)(src + (size_t)r * C);
                // stage full row: 20x 16B direct-to-LDS, all in flight
#pragma unroll
                for (int k = 0; k < 20; ++k) {
                    int idx = lane + (k << 6);
                    if (idx > ROWV4 - 1) idx = ROWV4 - 1;    // clamp (dup-load tail)
                    __builtin_amdgcn_global_load_lds(
                        (const __attribute__((address_space(1))) void*)(s4 + idx),
                        (__attribute__((address_space(3))) void*)(mybuf4 + (k << 6)),
                        16, 0, 0);
                }
                asm volatile("s_waitcnt vmcnt(0)" ::: "memory");

                const float v0 = mybuf[cls0];
                float v1 = NEGV;
                if (cls1 >= 0) v1 = mybuf[cls1];
                dstb[(size_t)r * RP + lane] = v0;
                if (lane + 64 < RP) dstb[(size_t)r * RP + lane + 64] = v1;
                ++done;
            }
            if (done) {
                __threadfence();
                if (lane == 0) atomicAdd(ctr + task, done);
            }
        }
        return;
    }

    // ================= alpha role =================
    float* buf0 = (float*)arena;                          // [CHE]
    float* buf1 = (float*)(arena + CHE * 4);              // [CHE]
    int*   tgt  = (int*)(arena + 2 * CHE * 4);            // [L]
    float* sm   = (float*)(arena + 2 * CHE * 4 + L * 4);  // [256]

    const int b  = bid;
    const int il = il_[b];
    const int nch = (il + CH - 1) / CH;
    const float* __restrict__ base = ws + (size_t)b * T_PAD * RP;

    if (tid < L) tgt[tid] = targets[b * L + tid];
    __syncthreads();

    const int lane = tid;
    const int s0   = 4 * lane;
    bool skip1 = false, skip3 = false;
    bool v0 = false, v1 = false, v2c = false, v3 = false;
    int  offt = 0;
    if (tid < 64) {
        const int l2 = 2 * lane;
        const int i1 = (l2     < L) ? l2     : L - 1;
        const int i3 = (l2 + 1 < L) ? l2 + 1 : L - 1;
        const int ip = (l2 - 1 >= 0) ? l2 - 1 : 0;
        const int c1i = tgt[i1], c3i = tgt[i3], cpi = tgt[ip];
        skip1 = (lane == 0) ? true : (c1i != cpi);
        skip3 = (c3i != c1i);
        v0  = (s0     < S);
        v1  = (s0 + 1 < S);
        v2c = (s0 + 2 < S);
        v3  = (s0 + 3 < S);
        offt = (l2 <= 100) ? l2 : 100;   // even -> 8B aligned float2
    }

    float a0 = NEGV, a1v = NEGV, a2v = NEGV, a3v = NEGV;

    for (int c = -1; c < nch; ++c) {
        if (tid >= 64) {
            // producers: wait for chunk c+1 completion, then dense copy
            const int c2 = c + 1;
            if (c2 < nch) {
                const int task = (c2 << 5) + b;
                const int rows = ((il - c2 * CH) < CH) ? (il - c2 * CH) : CH;
                while (__hip_atomic_load(ctr + task, __ATOMIC_ACQUIRE,
                                         __HIP_MEMORY_SCOPE_AGENT) < rows) {
                    __builtin_amdgcn_s_sleep(2);
                }
                const int jmax = rows * (RP / 4);
                float4* __restrict__ dst = (float4*)((c2 & 1) ? buf1 : buf0);
                const float4* __restrict__ src =
                    (const float4*)(base + (size_t)c2 * CHE);
                for (int j = tid - 64; j < jmax; j += 256) dst[j] = src[j];
            }
        } else if (c >= 0) {
            // consumer: process chunk c
            const float* bp = (c & 1) ? buf1 : buf0;
            const int tbase = c * CH;
            const int rmax  = (il - tbase < CH) ? (il - tbase) : CH;
            float2 tv = *(const float2*)(bp + offt);
            float  bl = bp[100];
            for (int r = 0; r < rmax; ++r) {
                const float2 ctv = tv;
                const float  cbl = bl;
                if (r + 1 < rmax) {
                    tv = *(const float2*)(bp + (r + 1) * RP + offt);
                    bl = bp[(r + 1) * RP + 100];
                }
                const int t = tbase + r;
                if (t == 0) {
                    a0  = (lane == 0) ? cbl   : NEGV;
                    a1v = (lane == 0) ? ctv.x : NEGV;
                    a2v = NEGV; a3v = NEGV;
                } else {
                    float up3 = __shfl_up(a3v, 1);   // state 4l-1
                    if (lane == 0) up3 = NEGV;
                    const float n0 = lse2(a0, up3) + cbl;
                    const float n1 = (skip1 ? lse3(a1v, a0, up3) : lse2(a1v, a0)) + ctv.x;
                    const float n2 = lse2(a2v, a1v) + cbl;
                    const float n3 = (skip3 ? lse3(a3v, a2v, a1v) : lse2(a3v, a2v)) + ctv.y;
                    a0  = v0  ? n0 : NEGV;
                    a1v = v1  ? n1 : NEGV;
                    a2v = v2c ? n2 : NEGV;
                    a3v = v3  ? n3 : NEGV;
                }
            }
        }
        __syncthreads();
    }

    if (tid < 64) {
        sm[s0 + 0] = a0;
        sm[s0 + 1] = a1v;
        sm[s0 + 2] = a2v;
        sm[s0 + 3] = a3v;
    }
    __syncthreads();

    if (tid == 0) {
        const int tl = tl_[b];
        const float tot = lse2(sm[2 * tl], sm[2 * tl - 1]);
        const bool finite = tot > (NEGV * 0.5f);
        atomicAdd(out + 0, finite ? tot : 0.0f);
        atomicAdd(out + 1, finite ? (float)il : 0.0f);
        atomicAdd(out + 2, (float)il);
    }
}

// ---------------------------------------------------------------------------
// Fallback: original fused kernel (used only if ws_size < WS_NEED).
// ---------------------------------------------------------------------------
constexpr int SPF  = 204;
constexpr int CHF  = 32;
constexpr int CHEF = CHF * SPF;
constexpr int NPROD = 256;

__global__ __launch_bounds__(BLK) void ctc_fused(
    const float* __restrict__ lp, const int* __restrict__ targets,
    const int* __restrict__ il_, const int* __restrict__ tl_,
    float* __restrict__ out)
{
    __shared__ float buf[2][CHEF];
    __shared__ int   tgt[L];
    __shared__ float sm[256];

    const int b   = blockIdx.x;
    const int tid = threadIdx.x;
    const int il  = il_[b];
    const int nch = (il + CHF - 1) / CHF;
    const float* __restrict__ base = lp + (size_t)b * T * C;

    if (tid < L) tgt[tid] = targets[b * L + tid];
    __syncthreads();

    const int lane = tid;
    const int s0   = 4 * lane;
    bool skip1 = false, skip3 = false;
    bool v0 = false, v1 = false, v2c = false, v3 = false;
    int  off = 0;
    if (tid < 64) {
        const int l2 = 2 * lane;
        const int i1 = (l2     < L) ? l2     : L - 1;
        const int i3 = (l2 + 1 < L) ? l2 + 1 : L - 1;
        const int ip = (l2 - 1 >= 0) ? l2 - 1 : 0;
        const int c1i = tgt[i1], c3i = tgt[i3], cpi = tgt[ip];
        skip1 = (lane == 0) ? true : (c1i != cpi);
        skip3 = (c3i != c1i);
        v0  = (s0     < S);
        v1  = (s0 + 1 < S);
        v2c = (s0 + 2 < S);
        v3  = (s0 + 3 < S);
        off = (s0 <= 200) ? s0 : 200;
    }

    float a0 = NEGV, a1v = NEGV, a2v = NEGV, a3v = NEGV;

    for (int c = -1; c < nch; ++c) {
        if (tid >= 64) {
            const int c2 = c + 1;
            if (c2 < nch) {
                float* dst = buf[c2 & 1];
                const int tbase = c2 * CHF;
                const int pid = tid - 64;
#pragma unroll
                for (int bat = 0; bat < 2; ++bat) {
                    float v[13];
                    int   fl[13];
#pragma unroll
                    for (int j = 0; j < 13; ++j) {
                        const int flat = (bat * 13 + j) * NPROD + pid;
                        fl[j] = flat;
                        float val = NEGV;
                        if (flat < CHEF) {
                            const int r = flat / SPF;
                            const int s = flat - r * SPF;
                            const int t = tbase + r;
                            if (t < il) {
                                const int cls = ((s & 1) && s < S) ? tgt[s >> 1] : 0;
                                val = base[(size_t)t * C + cls];
                            }
                        }
                        v[j] = val;
                    }
#pragma unroll
                    for (int j = 0; j < 13; ++j)
                        if (fl[j] < CHEF) dst[fl[j]] = v[j];
                }
            }
        } else if (c >= 0) {
            const float* bp = buf[c & 1];
            const int tbase = c * CHF;
            const int rmax  = (il - tbase < CHF) ? (il - tbase) : CHF;
            float4 e = *(const float4*)(bp + off);
            for (int r = 0; r < rmax; ++r) {
                const float4 cur = e;
                if (r + 1 < rmax) e = *(const float4*)(bp + (r + 1) * SPF + off);
                const int t = tbase + r;
                if (t == 0) {
                    a0  = (lane == 0) ? cur.x : NEGV;
                    a1v = (lane == 0) ? cur.y : NEGV;
                    a2v = NEGV; a3v = NEGV;
                } else {
                    float up3 = __shfl_up(a3v, 1);
                    if (lane == 0) up3 = NEGV;
                    const float n0 = lse2(a0, up3) + cur.x;
                    const float n1 = (skip1 ? lse3(a1v, a0, up3) : lse2(a1v, a0)) + cur.y;
                    const float n2 = lse2(a2v, a1v) + cur.z;
                    const float n3 = (skip3 ? lse3(a3v, a2v, a1v) : lse2(a3v, a2v)) + cur.w;
                    a0  = v0  ? n0 : NEGV;
                    a1v = v1  ? n1 : NEGV;
                    a2v = v2c ? n2 : NEGV;
                    a3v = v3  ? n3 : NEGV;
                }
            }
        }
        __syncthreads();
    }

    if (tid < 64) {
        sm[s0 + 0] = a0;
        sm[s0 + 1] = a1v;
        sm[s0 + 2] = a2v;
        sm[s0 + 3] = a3v;
    }
    __syncthreads();

    if (tid == 0) {
        const int tl = tl_[b];
        const float tot = lse2(sm[2 * tl], sm[2 * tl - 1]);
        const bool finite = tot > (NEGV * 0.5f);
        atomicAdd(out + 0, finite ? tot : 0.0f);
        atomicAdd(out + 1, finite ? (float)il : 0.0f);
        atomicAdd(out + 2, (float)il);
    }
}

extern "C" void kernel_launch(void* const* d_in, const int* in_sizes, int n_in,
                              void* d_out, int out_size, void* d_ws, size_t ws_size,
                              hipStream_t stream)
{
    const float* lp      = (const float*)d_in[0];   // (B,T,C) f32
    const int*   targets = (const int*)d_in[1];     // (B,L)
    const int*   il      = (const int*)d_in[2];     // (B,)
    const int*   tl      = (const int*)d_in[3];     // (B,)
    float* out = (float*)d_out;                     // 3 floats

    hipMemsetAsync(d_out, 0, (size_t)out_size * sizeof(float), stream);

    if (ws_size >= WS_NEED) {
        float* ws  = (float*)d_ws;
        int*  ctr  = (int*)(ws + DATA_FLOATS);
        hipMemsetAsync(ctr, 0, NT * sizeof(int), stream);
        ctc_pipe<<<NBLOCKS, BLK, 0, stream>>>(lp, targets, il, tl, out, ws, ctr);
    } else {
        ctc_fused<<<B, BLK, 0, stream>>>(lp, targets, il, tl, out);
    }
}